// Round 1
// baseline (235.002 us; speedup 1.0000x reference)
//
#include <hip/hip_runtime.h>

// Problem constants (from reference setup_inputs)
constexpr int K    = 64;
constexpr int N    = 1024;
constexpr int DIN  = 16;
constexpr int H1   = 4;
constexpr int DOUT = 8;
constexpr int FC1  = 54;

#define NEG_INF_F (-1e12f)
#define ALPHA_F   (0.01f)

// ---------------------------------------------------------------------------
// Kernel A: h1 = X @ W1  [K,N,4], f1 = h1 . a1[:4], f2 = h1 . a1[4:]
// one thread per (k,n)
// ---------------------------------------------------------------------------
__global__ void gat1_proj(const float* __restrict__ X,
                          const float* __restrict__ W1,
                          const float* __restrict__ a1,
                          float* __restrict__ h1,
                          float* __restrict__ f1,
                          float* __restrict__ f2) {
    int idx = blockIdx.x * blockDim.x + threadIdx.x;   // k*N + n
    if (idx >= K * N) return;
    const float* x = X + (size_t)idx * DIN;
    float h[H1] = {0.f, 0.f, 0.f, 0.f};
    #pragma unroll
    for (int d = 0; d < DIN; d++) {
        float xv = x[d];
        #pragma unroll
        for (int f = 0; f < H1; f++) h[f] += xv * W1[d * H1 + f];
    }
    float s1 = 0.f, s2 = 0.f;
    #pragma unroll
    for (int f = 0; f < H1; f++) { s1 += h[f] * a1[f]; s2 += h[f] * a1[H1 + f]; }
    *(float4*)(h1 + (size_t)idx * H1) = make_float4(h[0], h[1], h[2], h[3]);
    f1[idx] = s1;
    f2[idx] = s2;
}

// ---------------------------------------------------------------------------
// Kernel C: h2 = x1 @ W2  [K,N,8], f1/f2 from a2
// one thread per (k,n)
// ---------------------------------------------------------------------------
__global__ void gat2_proj(const float* __restrict__ x1,
                          const float* __restrict__ W2,
                          const float* __restrict__ a2,
                          float* __restrict__ h2,
                          float* __restrict__ f1,
                          float* __restrict__ f2) {
    int idx = blockIdx.x * blockDim.x + threadIdx.x;   // k*N + n
    if (idx >= K * N) return;
    float4 xv = *(const float4*)(x1 + (size_t)idx * H1);
    float h[DOUT];
    #pragma unroll
    for (int f = 0; f < DOUT; f++) {
        h[f] = xv.x * W2[0 * DOUT + f] + xv.y * W2[1 * DOUT + f]
             + xv.z * W2[2 * DOUT + f] + xv.w * W2[3 * DOUT + f];
    }
    float s1 = 0.f, s2 = 0.f;
    #pragma unroll
    for (int f = 0; f < DOUT; f++) { s1 += h[f] * a2[f]; s2 += h[f] * a2[DOUT + f]; }
    float* hp = h2 + (size_t)idx * DOUT;
    *(float4*)(hp)     = make_float4(h[0], h[1], h[2], h[3]);
    *(float4*)(hp + 4) = make_float4(h[4], h[5], h[6], h[7]);
    f1[idx] = s1;
    f2[idx] = s2;
}

// ---------------------------------------------------------------------------
// Kernel B/D: masked-softmax attention + aggregation + ReLU.
// One wave (64 lanes) per output row (k,i). Each lane owns 16 j's; e-values
// live in registers (fully unrolled), so no LDS / no __syncthreads needed.
// Row mapping is i-major so 64 consecutive waves share one adj row (L1/L2 hit).
// ---------------------------------------------------------------------------
template <int F>
__global__ void gat_attn(const int*   __restrict__ adj,
                         const float* __restrict__ h,
                         const float* __restrict__ f1,
                         const float* __restrict__ f2,
                         float*       __restrict__ out) {
    const int wave = threadIdx.x >> 6;
    const int lane = threadIdx.x & 63;
    const int r    = blockIdx.x * 4 + wave;   // 0 .. K*N-1
    const int i    = r >> 6;                  // node index (adj row), i-major
    const int k    = r & 63;                  // batch index
    const int row  = k * N + i;               // index into f1 / out

    const float f1i = f1[row];
    const int*   adjrow = adj + (size_t)i * N;
    const float* f2k    = f2 + (size_t)k * N;

    // Pass 1: e values into registers, running max.
    float e_loc[16];
    float m = -INFINITY;
    #pragma unroll
    for (int it = 0; it < 16; it++) {
        int j   = it * 64 + lane;
        float x = f1i + f2k[j];
        float e = fmaxf(x, ALPHA_F * x);           // leaky_relu(x, 0.01)
        e = (adjrow[j] > 0) ? e : NEG_INF_F;       // mask
        e_loc[it] = e;
        m = fmaxf(m, e);
    }
    #pragma unroll
    for (int off = 32; off > 0; off >>= 1) m = fmaxf(m, __shfl_xor(m, off));

    // Pass 2: exp, denominator, weighted sum of h rows.
    float s = 0.f;
    float acc[F];
    #pragma unroll
    for (int f = 0; f < F; f++) acc[f] = 0.f;
    const float* hk = h + (size_t)k * N * F;
    #pragma unroll
    for (int it = 0; it < 16; it++) {
        int j   = it * 64 + lane;
        float p = __expf(e_loc[it] - m);
        s += p;
        const float* hj = hk + (size_t)j * F;
        if (F == 4) {
            float4 hv = *(const float4*)hj;
            acc[0] += p * hv.x; acc[1] += p * hv.y;
            acc[2] += p * hv.z; acc[3] += p * hv.w;
        } else {
            float4 h0 = *(const float4*)hj;
            float4 h1v = *(const float4*)(hj + 4);
            acc[0] += p * h0.x;  acc[1] += p * h0.y;
            acc[2] += p * h0.z;  acc[3] += p * h0.w;
            acc[4] += p * h1v.x; acc[5] += p * h1v.y;
            acc[6] += p * h1v.z; acc[7] += p * h1v.w;
        }
    }
    #pragma unroll
    for (int off = 32; off > 0; off >>= 1) {
        s += __shfl_xor(s, off);
        #pragma unroll
        for (int f = 0; f < F; f++) acc[f] += __shfl_xor(acc[f], off);
    }

    if (lane == 0) {
        float inv = 1.f / s;
        float* o = out + (size_t)row * F;
        if (F == 4) {
            *(float4*)o = make_float4(fmaxf(acc[0] * inv, 0.f),
                                      fmaxf(acc[1] * inv, 0.f),
                                      fmaxf(acc[2] * inv, 0.f),
                                      fmaxf(acc[3] * inv, 0.f));
        } else {
            *(float4*)o       = make_float4(fmaxf(acc[0] * inv, 0.f),
                                            fmaxf(acc[1] * inv, 0.f),
                                            fmaxf(acc[2] * inv, 0.f),
                                            fmaxf(acc[3] * inv, 0.f));
            *(float4*)(o + 4) = make_float4(fmaxf(acc[4] * inv, 0.f),
                                            fmaxf(acc[5] * inv, 0.f),
                                            fmaxf(acc[6] * inv, 0.f),
                                            fmaxf(acc[7] * inv, 0.f));
        }
    }
}

// ---------------------------------------------------------------------------
// Transpose fc1_w [8192, 54] -> wt [54, 8192] for coalesced FC1 dots.
// ---------------------------------------------------------------------------
__global__ void transpose_w(const float* __restrict__ w, float* __restrict__ wt) {
    int tid = blockIdx.x * blockDim.x + threadIdx.x;   // c*8192 + m
    if (tid >= FC1 * N * DOUT) return;
    int c = tid >> 13;
    int m = tid & 8191;
    wt[tid] = w[(size_t)m * FC1 + c];
}

// ---------------------------------------------------------------------------
// FC1: y[k,c] = relu( x2[k,:] . wt[c,:] + b[c] ).  One wave per (k,c).
// ---------------------------------------------------------------------------
__global__ void fc1_kernel(const float* __restrict__ x2,
                           const float* __restrict__ wt,
                           const float* __restrict__ b,
                           float* __restrict__ y) {
    int bid  = blockIdx.x;            // k*54 + c
    int k    = bid / FC1;
    int c    = bid - k * FC1;
    int lane = threadIdx.x;
    const float4* x4 = (const float4*)(x2 + (size_t)k * N * DOUT);
    const float4* w4 = (const float4*)(wt + (size_t)c * N * DOUT);
    float s = 0.f;
    #pragma unroll 4
    for (int m = lane; m < (N * DOUT) / 4; m += 64) {
        float4 a = x4[m], w = w4[m];
        s += a.x * w.x + a.y * w.y + a.z * w.z + a.w * w.w;
    }
    #pragma unroll
    for (int off = 32; off > 0; off >>= 1) s += __shfl_xor(s, off);
    if (lane == 0) y[bid] = fmaxf(s + b[c], 0.f);
}

// ---------------------------------------------------------------------------
// Final: out[k,n] = y[k,:] . out_w[:,n] + out_b[n].  One thread per (k,n).
// ---------------------------------------------------------------------------
__global__ void fc2_kernel(const float* __restrict__ y,
                           const float* __restrict__ out_w,
                           const float* __restrict__ out_b,
                           float* __restrict__ out) {
    int n = blockIdx.x * blockDim.x + threadIdx.x;   // 0..1023
    int k = blockIdx.y;
    const float* yk = y + (size_t)k * FC1;
    float s = out_b[n];
    #pragma unroll 6
    for (int c = 0; c < FC1; c++) s += yk[c] * out_w[(size_t)c * N + n];
    out[(size_t)k * N + n] = s;
}

// ---------------------------------------------------------------------------
extern "C" void kernel_launch(void* const* d_in, const int* in_sizes, int n_in,
                              void* d_out, int out_size, void* d_ws, size_t ws_size,
                              hipStream_t stream) {
    const float* X     = (const float*)d_in[0];
    const int*   adj   = (const int*)  d_in[1];
    const float* W1    = (const float*)d_in[2];
    const float* a1    = (const float*)d_in[3];
    const float* W2    = (const float*)d_in[4];
    const float* a2    = (const float*)d_in[5];
    const float* fc1w  = (const float*)d_in[6];
    const float* fc1b  = (const float*)d_in[7];
    const float* outw  = (const float*)d_in[8];
    const float* outb  = (const float*)d_in[9];
    float* out = (float*)d_out;

    // Workspace layout (floats)
    float* ws  = (float*)d_ws;
    float* h1  = ws;                       // 64*1024*4   = 262144
    float* f11 = h1  + 262144;             // 65536
    float* f21 = f11 + 65536;              // 65536
    float* x1  = f21 + 65536;              // 262144
    float* h2  = x1  + 262144;             // 524288
    float* f12 = h2  + 524288;             // 65536
    float* f22 = f12 + 65536;              // 65536
    float* x2  = f22 + 65536;              // 524288
    float* y   = x2  + 524288;             // 4096 (3456 used)
    float* wt  = y   + 4096;               // 442368
    // total ~2.28M floats = 9.1 MB

    // fc1_w transpose (independent of GAT chain, but same stream = ordered)
    transpose_w<<<dim3((FC1 * N * DOUT + 255) / 256), dim3(256), 0, stream>>>(fc1w, wt);

    // Layer 1
    gat1_proj<<<dim3(K * N / 256), dim3(256), 0, stream>>>(X, W1, a1, h1, f11, f21);
    gat_attn<4><<<dim3(K * N / 4), dim3(256), 0, stream>>>(adj, h1, f11, f21, x1);

    // Layer 2
    gat2_proj<<<dim3(K * N / 256), dim3(256), 0, stream>>>(x1, W2, a2, h2, f12, f22);
    gat_attn<8><<<dim3(K * N / 4), dim3(256), 0, stream>>>(adj, h2, f12, f22, x2);

    // FC head
    fc1_kernel<<<dim3(K * FC1), dim3(64), 0, stream>>>(x2, wt, fc1b, y);
    fc2_kernel<<<dim3(N / 256, K), dim3(256), 0, stream>>>(y, outw, outb, out);
}

// Round 2
// 205.133 us; speedup vs baseline: 1.1456x; 1.1456x over previous
//
#include <hip/hip_runtime.h>

// Problem constants (from reference setup_inputs)
constexpr int K    = 64;
constexpr int N    = 1024;
constexpr int DIN  = 16;
constexpr int H1   = 4;
constexpr int DOUT = 8;
constexpr int FC1  = 54;

#define NEG_INF_F (-1e12f)
#define ALPHA_F   (0.01f)

// ---------------------------------------------------------------------------
// Pack adjacency into bits: mbits[i*16+lg] = uint2 (lo,hi); bit t of (lo,hi)
// = adj[i][t*16+lg] > 0.   (k-independent mask, read 64x per layer otherwise)
// ---------------------------------------------------------------------------
__global__ void pack_mask(const int* __restrict__ adj, uint2* __restrict__ mbits) {
    int tid = blockIdx.x * blockDim.x + threadIdx.x;   // i*16 + lg
    if (tid >= N * 16) return;
    int i  = tid >> 4;
    int lg = tid & 15;
    const int* arow = adj + (size_t)i * N + lg;
    unsigned lo = 0u, hi = 0u;
    #pragma unroll
    for (int t = 0; t < 32; t++)  lo |= (arow[t * 16] > 0 ? 1u : 0u) << t;
    #pragma unroll
    for (int t = 32; t < 64; t++) hi |= (arow[t * 16] > 0 ? 1u : 0u) << (t - 32);
    mbits[tid] = make_uint2(lo, hi);
}

// ---------------------------------------------------------------------------
// Kernel A: h1 = X @ W1  [K,N,4], f1 = h1 . a1[:4], f2 = h1 . a1[4:]
// one thread per (k,n)
// ---------------------------------------------------------------------------
__global__ void gat1_proj(const float* __restrict__ X,
                          const float* __restrict__ W1,
                          const float* __restrict__ a1,
                          float* __restrict__ h1,
                          float* __restrict__ f1,
                          float* __restrict__ f2) {
    int idx = blockIdx.x * blockDim.x + threadIdx.x;   // k*N + n
    if (idx >= K * N) return;
    const float4* x4 = (const float4*)(X + (size_t)idx * DIN);
    float h[H1] = {0.f, 0.f, 0.f, 0.f};
    #pragma unroll
    for (int q = 0; q < 4; q++) {
        float4 xv = x4[q];
        #pragma unroll
        for (int f = 0; f < H1; f++) {
            h[f] += xv.x * W1[(q * 4 + 0) * H1 + f] + xv.y * W1[(q * 4 + 1) * H1 + f]
                  + xv.z * W1[(q * 4 + 2) * H1 + f] + xv.w * W1[(q * 4 + 3) * H1 + f];
        }
    }
    float s1 = 0.f, s2 = 0.f;
    #pragma unroll
    for (int f = 0; f < H1; f++) { s1 += h[f] * a1[f]; s2 += h[f] * a1[H1 + f]; }
    *(float4*)(h1 + (size_t)idx * H1) = make_float4(h[0], h[1], h[2], h[3]);
    f1[idx] = s1;
    f2[idx] = s2;
}

// ---------------------------------------------------------------------------
// Kernel C: h2 = x1 @ W2  [K,N,8], f1/f2 from a2
// ---------------------------------------------------------------------------
__global__ void gat2_proj(const float* __restrict__ x1,
                          const float* __restrict__ W2,
                          const float* __restrict__ a2,
                          float* __restrict__ h2,
                          float* __restrict__ f1,
                          float* __restrict__ f2) {
    int idx = blockIdx.x * blockDim.x + threadIdx.x;   // k*N + n
    if (idx >= K * N) return;
    float4 xv = *(const float4*)(x1 + (size_t)idx * H1);
    float h[DOUT];
    #pragma unroll
    for (int f = 0; f < DOUT; f++) {
        h[f] = xv.x * W2[0 * DOUT + f] + xv.y * W2[1 * DOUT + f]
             + xv.z * W2[2 * DOUT + f] + xv.w * W2[3 * DOUT + f];
    }
    float s1 = 0.f, s2 = 0.f;
    #pragma unroll
    for (int f = 0; f < DOUT; f++) { s1 += h[f] * a2[f]; s2 += h[f] * a2[DOUT + f]; }
    float* hp = h2 + (size_t)idx * DOUT;
    *(float4*)(hp)     = make_float4(h[0], h[1], h[2], h[3]);
    *(float4*)(hp + 4) = make_float4(h[4], h[5], h[6], h[7]);
    f1[idx] = s1;
    f2[idx] = s2;
}

// ---------------------------------------------------------------------------
// Attention v2: 16 lanes per (k,i) row; 4 rows per wave (parallel lane
// groups); block = one k x 16 i rows (4 waves). Single-pass softmax (no
// max-subtract: |e| <= ~25 so exp can't overflow; masked -> exp(-1e12)=0).
// Mask from packed bits (scalar-indexed shift; no VMEM in hot loop).
// Reduction: 4 butterfly levels within each 16-lane group.
// ---------------------------------------------------------------------------
template <int F>
__global__ __launch_bounds__(256) void gat_attn2(
        const uint2* __restrict__ mbits,   // [N*16]
        const float* __restrict__ h,       // [K,N,F]
        const float* __restrict__ f1,      // [K,N]
        const float* __restrict__ f2,      // [K,N]
        float*       __restrict__ out) {   // [K,N,F]
    const int wave = threadIdx.x >> 6;
    const int lane = threadIdx.x & 63;
    const int g    = lane >> 4;            // lane group = row within wave
    const int lg   = lane & 15;
    const int k    = blockIdx.x & 63;      // i-major block order
    const int i16  = blockIdx.x >> 6;
    const int i    = i16 * 16 + wave * 4 + g;
    const int row  = k * N + i;

    const float f1i = f1[row];
    const uint2 mw  = mbits[i * 16 + lg];
    const float* f2k = f2 + (size_t)k * N;
    const float* hk  = h + (size_t)k * N * F;

    float s = 0.f;
    float acc[F];
    #pragma unroll
    for (int f = 0; f < F; f++) acc[f] = 0.f;
    const float neg = NEG_INF_F;

    #pragma unroll 8
    for (int t = 0; t < 64; t++) {
        int j    = (t << 4) + lg;
        float x  = f1i + f2k[j];
        float e  = fmaxf(x, ALPHA_F * x);              // leaky_relu
        unsigned w = (t & 32) ? mw.y : mw.x;           // uniform select
        int sh = (int)(w << (31 - (t & 31)));          // bit t -> sign
        e = (sh < 0) ? e : neg;                        // mask
        float p = __expf(e);
        s += p;
        const float* hj = hk + (size_t)j * F;
        if (F == 4) {
            float4 hv = *(const float4*)hj;
            acc[0] += p * hv.x; acc[1] += p * hv.y;
            acc[2] += p * hv.z; acc[3] += p * hv.w;
        } else {
            float4 h0 = *(const float4*)hj;
            float4 h1v = *(const float4*)(hj + 4);
            acc[0] += p * h0.x;  acc[1] += p * h0.y;
            acc[2] += p * h0.z;  acc[3] += p * h0.w;
            acc[4] += p * h1v.x; acc[5] += p * h1v.y;
            acc[6] += p * h1v.z; acc[7] += p * h1v.w;
        }
    }

    // reduce within each 16-lane group
    #pragma unroll
    for (int off = 8; off >= 1; off >>= 1) {
        s += __shfl_xor(s, off);
        #pragma unroll
        for (int f = 0; f < F; f++) acc[f] += __shfl_xor(acc[f], off);
    }

    if (lg == 0) {
        float inv = (s > 0.f) ? 1.f / s : 0.f;
        float* o = out + (size_t)row * F;
        if (F == 4) {
            *(float4*)o = make_float4(fmaxf(acc[0] * inv, 0.f),
                                      fmaxf(acc[1] * inv, 0.f),
                                      fmaxf(acc[2] * inv, 0.f),
                                      fmaxf(acc[3] * inv, 0.f));
        } else {
            *(float4*)o       = make_float4(fmaxf(acc[0] * inv, 0.f),
                                            fmaxf(acc[1] * inv, 0.f),
                                            fmaxf(acc[2] * inv, 0.f),
                                            fmaxf(acc[3] * inv, 0.f));
            *(float4*)(o + 4) = make_float4(fmaxf(acc[4] * inv, 0.f),
                                            fmaxf(acc[5] * inv, 0.f),
                                            fmaxf(acc[6] * inv, 0.f),
                                            fmaxf(acc[7] * inv, 0.f));
        }
    }
}

// ---------------------------------------------------------------------------
// Transpose fc1_w [8192, 54] -> wt [54, 8192] for coalesced FC1 dots.
// ---------------------------------------------------------------------------
__global__ void transpose_w(const float* __restrict__ w, float* __restrict__ wt) {
    int tid = blockIdx.x * blockDim.x + threadIdx.x;   // c*8192 + m
    if (tid >= FC1 * N * DOUT) return;
    int c = tid >> 13;
    int m = tid & 8191;
    wt[tid] = w[(size_t)m * FC1 + c];
}

// ---------------------------------------------------------------------------
// FC1: y[k,c] = relu( x2[k,:] . wt[c,:] + b[c] ).  One wave per (k,c).
// ---------------------------------------------------------------------------
__global__ void fc1_kernel(const float* __restrict__ x2,
                           const float* __restrict__ wt,
                           const float* __restrict__ b,
                           float* __restrict__ y) {
    int bid  = blockIdx.x;            // k*54 + c
    int k    = bid / FC1;
    int c    = bid - k * FC1;
    int lane = threadIdx.x;
    const float4* x4 = (const float4*)(x2 + (size_t)k * N * DOUT);
    const float4* w4 = (const float4*)(wt + (size_t)c * N * DOUT);
    float s = 0.f;
    #pragma unroll 4
    for (int m = lane; m < (N * DOUT) / 4; m += 64) {
        float4 a = x4[m], w = w4[m];
        s += a.x * w.x + a.y * w.y + a.z * w.z + a.w * w.w;
    }
    #pragma unroll
    for (int off = 32; off > 0; off >>= 1) s += __shfl_xor(s, off);
    if (lane == 0) y[bid] = fmaxf(s + b[c], 0.f);
}

// ---------------------------------------------------------------------------
// Final: out[k,n] = y[k,:] . out_w[:,n] + out_b[n].  One thread per (k,n).
// ---------------------------------------------------------------------------
__global__ void fc2_kernel(const float* __restrict__ y,
                           const float* __restrict__ out_w,
                           const float* __restrict__ out_b,
                           float* __restrict__ out) {
    int n = blockIdx.x * blockDim.x + threadIdx.x;   // 0..1023
    int k = blockIdx.y;
    const float* yk = y + (size_t)k * FC1;
    float s = out_b[n];
    #pragma unroll 6
    for (int c = 0; c < FC1; c++) s += yk[c] * out_w[(size_t)c * N + n];
    out[(size_t)k * N + n] = s;
}

// ---------------------------------------------------------------------------
extern "C" void kernel_launch(void* const* d_in, const int* in_sizes, int n_in,
                              void* d_out, int out_size, void* d_ws, size_t ws_size,
                              hipStream_t stream) {
    const float* X     = (const float*)d_in[0];
    const int*   adj   = (const int*)  d_in[1];
    const float* W1    = (const float*)d_in[2];
    const float* a1    = (const float*)d_in[3];
    const float* W2    = (const float*)d_in[4];
    const float* a2    = (const float*)d_in[5];
    const float* fc1w  = (const float*)d_in[6];
    const float* fc1b  = (const float*)d_in[7];
    const float* outw  = (const float*)d_in[8];
    const float* outb  = (const float*)d_in[9];
    float* out = (float*)d_out;

    // Workspace layout (floats)
    float* ws  = (float*)d_ws;
    float* h1  = ws;                       // 262144
    float* f11 = h1  + 262144;             // 65536
    float* f21 = f11 + 65536;              // 65536
    float* x1  = f21 + 65536;              // 262144
    float* h2  = x1  + 262144;             // 524288
    float* f12 = h2  + 524288;             // 65536
    float* f22 = f12 + 65536;              // 65536
    float* x2  = f22 + 65536;              // 524288
    float* y   = x2  + 524288;             // 4096 (3456 used)
    float* wt  = y   + 4096;               // 442368
    uint2* mb  = (uint2*)(wt + 442368);    // 16384 uint2 = 128 KB
    // total ~9.3 MB

    // k-independent precomputes
    pack_mask  <<<dim3(N * 16 / 256), dim3(256), 0, stream>>>(adj, mb);
    transpose_w<<<dim3((FC1 * N * DOUT + 255) / 256), dim3(256), 0, stream>>>(fc1w, wt);

    // Layer 1
    gat1_proj<<<dim3(K * N / 256), dim3(256), 0, stream>>>(X, W1, a1, h1, f11, f21);
    gat_attn2<4><<<dim3(K * N / 16), dim3(256), 0, stream>>>(mb, h1, f11, f21, x1);

    // Layer 2
    gat2_proj<<<dim3(K * N / 256), dim3(256), 0, stream>>>(x1, W2, a2, h2, f12, f22);
    gat_attn2<8><<<dim3(K * N / 16), dim3(256), 0, stream>>>(mb, h2, f12, f22, x2);

    // FC head
    fc1_kernel<<<dim3(K * FC1), dim3(64), 0, stream>>>(x2, wt, fc1b, y);
    fc2_kernel<<<dim3(N / 256, K), dim3(256), 0, stream>>>(y, outw, outb, out);
}

// Round 3
// 202.845 us; speedup vs baseline: 1.1585x; 1.0113x over previous
//
#include <hip/hip_runtime.h>

// Problem constants (from reference setup_inputs)
constexpr int K    = 64;
constexpr int N    = 1024;
constexpr int DIN  = 16;
constexpr int H1   = 4;
constexpr int DOUT = 8;
constexpr int FC1  = 54;

#define ALPHA_F   (0.01f)

// ---------------------------------------------------------------------------
// prep kernel: three independent jobs split by blockIdx range.
//  A) blocks [0,2048):    maskT[jw*N+i] = ballot bits of adj[i][jw*64+lane]
//  B) blocks [2048,2912): wt[c*8192+m] = fc1_w[m*54+c]   (transpose)
//  C) blocks [2912,3040): gat1 projection: h1 = X@W1, f11/f21 attention logits
// ---------------------------------------------------------------------------
__global__ __launch_bounds__(512) void prep_kernel(
        const int* __restrict__ adj, unsigned long long* __restrict__ maskT,
        const float* __restrict__ fc1w, float* __restrict__ wt,
        const float* __restrict__ X, const float* __restrict__ W1,
        const float* __restrict__ a1,
        float* __restrict__ h1, float* __restrict__ f11, float* __restrict__ f21) {
    int b = blockIdx.x;
    if (b < 2048) {
        int wave = threadIdx.x >> 6, lane = threadIdx.x & 63;
        int wid = b * 8 + wave;            // 0..16383
        int jw  = wid >> 10;               // 0..15
        int i   = wid & 1023;
        int v = adj[i * N + (jw << 6) + lane];        // coalesced 256B/wave
        unsigned long long m = __ballot(v > 0);       // bit lane = adj>0
        if (lane == 0) maskT[jw * N + i] = m;
    } else if (b < 2912) {
        int tid = (b - 2048) * 512 + threadIdx.x;     // < 442368
        int c = tid >> 13, m = tid & 8191;
        wt[tid] = fc1w[(size_t)m * FC1 + c];
    } else {
        int idx = (b - 2912) * 512 + threadIdx.x;     // < 65536 : k*N+n
        const float4* x4 = (const float4*)(X + (size_t)idx * DIN);
        float h[H1] = {0.f, 0.f, 0.f, 0.f};
        #pragma unroll
        for (int q = 0; q < 4; q++) {
            float4 xv = x4[q];
            #pragma unroll
            for (int f = 0; f < H1; f++) {
                h[f] += xv.x * W1[(q * 4 + 0) * H1 + f] + xv.y * W1[(q * 4 + 1) * H1 + f]
                      + xv.z * W1[(q * 4 + 2) * H1 + f] + xv.w * W1[(q * 4 + 3) * H1 + f];
            }
        }
        float s1 = 0.f, s2 = 0.f;
        #pragma unroll
        for (int f = 0; f < H1; f++) { s1 += h[f] * a1[f]; s2 += h[f] * a1[H1 + f]; }
        *(float4*)(h1 + (size_t)idx * H1) = make_float4(h[0], h[1], h[2], h[3]);
        f11[idx] = s1;
        f21[idx] = s2;
    }
}

// ---------------------------------------------------------------------------
// Attention v3: one LANE per row i (64 rows per wave), j loop sequential.
// f2[j] / h[j][:] are wave-uniform (broadcast loads); mask bit per (lane,j)
// from transposed packed bits; zero cross-lane reduction for the row state.
// j-range split across the block's 8 waves (128 j each); LDS combine.
// Single-pass softmax (no max-subtract; masked lanes get exact p=0).
// FUSE: apply layer-2 projection (W2,a2) in the epilogue, skipping x1.
// ---------------------------------------------------------------------------
template <int F, bool FUSE>
__global__ __launch_bounds__(512) void gat_attn3(
        const unsigned long long* __restrict__ maskT,  // [16][N]
        const float* __restrict__ h,    // [K,N,F]
        const float* __restrict__ f1,   // [K,N]
        const float* __restrict__ f2,   // [K,N]
        const float* __restrict__ W2,   // [4,8]  (FUSE only)
        const float* __restrict__ a2,   // [16]   (FUSE only)
        float* __restrict__ o_x,        // FUSE: h2 [K,N,8]; else attn out [K,N,F]
        float* __restrict__ o_f1,       // FUSE: f12
        float* __restrict__ o_f2) {     // FUSE: f22
    const int wave = threadIdx.x >> 6;
    const int lane = threadIdx.x & 63;
    const int k    = blockIdx.x >> 4;
    const int iset = blockIdx.x & 15;
    const int i    = iset * 64 + lane;
    const int row  = k * N + i;

    const float  f1i = f1[row];
    const float* f2k = f2 + k * N;
    const float4* hk4 = (const float4*)(h + (size_t)(k * N) * F);

    float s = 0.f;
    float acc[F];
    #pragma unroll
    for (int f = 0; f < F; f++) acc[f] = 0.f;

    const int j0 = wave * 128;                       // this wave's j chunk
    #pragma unroll
    for (int jw2 = 0; jw2 < 2; jw2++) {
        const int jwbase = j0 + jw2 * 64;
        unsigned long long mw = maskT[(jwbase >> 6) * N + i];   // coalesced
        unsigned mh[2] = {(unsigned)mw, (unsigned)(mw >> 32)};
        #pragma unroll
        for (int half = 0; half < 2; half++) {
            const unsigned wb = mh[half];
            const int jb = jwbase + half * 32;
            const float*  f2p = f2k + jb;
            const float4* hp  = hk4 + (size_t)jb * (F / 4);
            #pragma unroll
            for (int t = 0; t < 32; t++) {
                float x = f1i + f2p[t];              // f2p[t] wave-uniform
                float e = fmaxf(x, ALPHA_F * x);     // leaky_relu
                float p = __expf(e);
                p = (wb & (1u << t)) ? p : 0.f;      // mask -> exact 0
                s += p;
                float4 h0 = hp[t * (F / 4)];         // wave-uniform
                acc[0] += p * h0.x; acc[1] += p * h0.y;
                acc[2] += p * h0.z; acc[3] += p * h0.w;
                if (F == 8) {
                    float4 h1v = hp[t * 2 + 1];
                    acc[4] += p * h1v.x; acc[5] += p * h1v.y;
                    acc[6] += p * h1v.z; acc[7] += p * h1v.w;
                }
            }
        }
    }

    // combine the 8 waves' partials (stride 9/5 floats -> conflict-free)
    __shared__ float part[8][64][F + 1];
    part[wave][lane][0] = s;
    #pragma unroll
    for (int f = 0; f < F; f++) part[wave][lane][1 + f] = acc[f];
    __syncthreads();

    if (threadIdx.x < 64) {
        const int r = threadIdx.x;
        float st = 0.f;
        float at[F];
        #pragma unroll
        for (int f = 0; f < F; f++) at[f] = 0.f;
        #pragma unroll
        for (int w = 0; w < 8; w++) {
            st += part[w][r][0];
            #pragma unroll
            for (int f = 0; f < F; f++) at[f] += part[w][r][1 + f];
        }
        const float inv = 1.f / st;
        const int orow = k * N + iset * 64 + r;
        float xo[F];
        #pragma unroll
        for (int f = 0; f < F; f++) xo[f] = fmaxf(at[f] * inv, 0.f);  // relu

        if constexpr (FUSE) {
            // layer-2 projection: h2 = xo(4) @ W2(4x8); logits vs a2
            float hv[DOUT];
            #pragma unroll
            for (int f = 0; f < DOUT; f++) {
                hv[f] = xo[0] * W2[f]      + xo[1] * W2[8 + f]
                      + xo[2] * W2[16 + f] + xo[3] * W2[24 + f];
            }
            float s1 = 0.f, s2 = 0.f;
            #pragma unroll
            for (int f = 0; f < DOUT; f++) { s1 += hv[f] * a2[f]; s2 += hv[f] * a2[DOUT + f]; }
            float* op = o_x + (size_t)orow * DOUT;
            *(float4*)op       = make_float4(hv[0], hv[1], hv[2], hv[3]);
            *(float4*)(op + 4) = make_float4(hv[4], hv[5], hv[6], hv[7]);
            o_f1[orow] = s1;
            o_f2[orow] = s2;
        } else {
            float* op = o_x + (size_t)orow * F;
            *(float4*)op = make_float4(xo[0], xo[1], xo[2], xo[3]);
            if (F == 8)
                *(float4*)(op + 4) = make_float4(xo[4], xo[5], xo[6], xo[7]);
        }
    }
}

// ---------------------------------------------------------------------------
// FC1: y[k,c] = relu( x2[k,:] . wt[c,:] + b[c] ).  One wave per (k,c).
// ---------------------------------------------------------------------------
__global__ void fc1_kernel(const float* __restrict__ x2,
                           const float* __restrict__ wt,
                           const float* __restrict__ b,
                           float* __restrict__ y) {
    int bid  = blockIdx.x;            // k*54 + c
    int k    = bid / FC1;
    int c    = bid - k * FC1;
    int lane = threadIdx.x;
    const float4* x4 = (const float4*)(x2 + (size_t)k * N * DOUT);
    const float4* w4 = (const float4*)(wt + (size_t)c * N * DOUT);
    float s = 0.f;
    #pragma unroll 4
    for (int m = lane; m < (N * DOUT) / 4; m += 64) {
        float4 a = x4[m], w = w4[m];
        s += a.x * w.x + a.y * w.y + a.z * w.z + a.w * w.w;
    }
    #pragma unroll
    for (int off = 32; off > 0; off >>= 1) s += __shfl_xor(s, off);
    if (lane == 0) y[bid] = fmaxf(s + b[c], 0.f);
}

// ---------------------------------------------------------------------------
// Final: out[k,n] = y[k,:] . out_w[:,n] + out_b[n].  One thread per (k,n).
// ---------------------------------------------------------------------------
__global__ void fc2_kernel(const float* __restrict__ y,
                           const float* __restrict__ out_w,
                           const float* __restrict__ out_b,
                           float* __restrict__ out) {
    int n = blockIdx.x * blockDim.x + threadIdx.x;   // 0..1023
    int k = blockIdx.y;
    const float* yk = y + (size_t)k * FC1;
    float s = out_b[n];
    #pragma unroll 6
    for (int c = 0; c < FC1; c++) s += yk[c] * out_w[(size_t)c * N + n];
    out[(size_t)k * N + n] = s;
}

// ---------------------------------------------------------------------------
extern "C" void kernel_launch(void* const* d_in, const int* in_sizes, int n_in,
                              void* d_out, int out_size, void* d_ws, size_t ws_size,
                              hipStream_t stream) {
    const float* X     = (const float*)d_in[0];
    const int*   adj   = (const int*)  d_in[1];
    const float* W1    = (const float*)d_in[2];
    const float* a1    = (const float*)d_in[3];
    const float* W2    = (const float*)d_in[4];
    const float* a2    = (const float*)d_in[5];
    const float* fc1w  = (const float*)d_in[6];
    const float* fc1b  = (const float*)d_in[7];
    const float* outw  = (const float*)d_in[8];
    const float* outb  = (const float*)d_in[9];
    float* out = (float*)d_out;

    // Workspace layout (floats); ~8.05 MB total
    float* ws  = (float*)d_ws;
    float* h1  = ws;                       // 262144
    float* f11 = h1  + 262144;             // 65536
    float* f21 = f11 + 65536;              // 65536
    float* h2  = f21 + 65536;              // 524288
    float* f12 = h2  + 524288;             // 65536
    float* f22 = f12 + 65536;              // 65536
    float* x2  = f22 + 65536;              // 524288
    float* y   = x2  + 524288;             // 4096 (3456 used)
    float* wt  = y   + 4096;               // 442368
    unsigned long long* mT = (unsigned long long*)(wt + 442368);  // 16384 u64

    // 1) fused prep: mask pack (transposed) + fc1_w transpose + gat1 proj
    prep_kernel<<<dim3(3040), dim3(512), 0, stream>>>(
        adj, mT, fc1w, wt, X, W1, a1, h1, f11, f21);

    // 2) layer-1 attention, fused with layer-2 projection
    gat_attn3<4, true><<<dim3(K * N / 64), dim3(512), 0, stream>>>(
        mT, h1, f11, f21, W2, a2, h2, f12, f22);

    // 3) layer-2 attention
    gat_attn3<8, false><<<dim3(K * N / 64), dim3(512), 0, stream>>>(
        mT, h2, f12, f22, nullptr, nullptr, x2, nullptr, nullptr);

    // 4) FC head
    fc1_kernel<<<dim3(K * FC1), dim3(64), 0, stream>>>(x2, wt, fc1b, y);
    fc2_kernel<<<dim3(N / 256, K), dim3(256), 0, stream>>>(y, outw, outb, out);
}

// Round 4
// 176.836 us; speedup vs baseline: 1.3289x; 1.1471x over previous
//
#include <hip/hip_runtime.h>

// Problem constants (from reference setup_inputs)
constexpr int K    = 64;
constexpr int N    = 1024;
constexpr int DIN  = 16;
constexpr int H1   = 4;
constexpr int DOUT = 8;
constexpr int FC1  = 54;

#define ALPHA_F   (0.01f)
#define LOG2E_F   (1.4426950408889634f)

__device__ inline float fast_exp2(float x) {
#if __has_builtin(__builtin_amdgcn_exp2f)
    return __builtin_amdgcn_exp2f(x);      // raw v_exp_f32
#else
    return __expf(x * 0.6931471805599453f);
#endif
}

// ---------------------------------------------------------------------------
// prep kernel: three independent jobs split by blockIdx range.
//  A) blocks [0,2048):    maskT[jw*N+i] = ballot bits of adj[i][jw*64+lane]
//  B) blocks [2048,2912): wt[c*8192+m] = fc1_w[m*54+c]   (transpose)
//  C) blocks [2912,3040): gat1 projection: h1 = X@W1; f11/f21 logits *log2e
// ---------------------------------------------------------------------------
__global__ __launch_bounds__(512) void prep_kernel(
        const int* __restrict__ adj, unsigned long long* __restrict__ maskT,
        const float* __restrict__ fc1w, float* __restrict__ wt,
        const float* __restrict__ X, const float* __restrict__ W1,
        const float* __restrict__ a1,
        float* __restrict__ h1, float* __restrict__ f11, float* __restrict__ f21) {
    int b = blockIdx.x;
    if (b < 2048) {
        int wave = threadIdx.x >> 6, lane = threadIdx.x & 63;
        int wid = b * 8 + wave;            // 0..16383
        int jw  = wid >> 10;               // 0..15
        int i   = wid & 1023;
        int v = adj[i * N + (jw << 6) + lane];        // coalesced 256B/wave
        unsigned long long m = __ballot(v > 0);       // bit lane = adj>0
        if (lane == 0) maskT[jw * N + i] = m;
    } else if (b < 2912) {
        int tid = (b - 2048) * 512 + threadIdx.x;     // < 442368
        int c = tid >> 13, m = tid & 8191;
        wt[tid] = fc1w[(size_t)m * FC1 + c];
    } else {
        int idx = (b - 2912) * 512 + threadIdx.x;     // < 65536 : k*N+n
        const float4* x4 = (const float4*)(X + (size_t)idx * DIN);
        float h[H1] = {0.f, 0.f, 0.f, 0.f};
        #pragma unroll
        for (int q = 0; q < 4; q++) {
            float4 xv = x4[q];
            #pragma unroll
            for (int f = 0; f < H1; f++) {
                h[f] += xv.x * W1[(q * 4 + 0) * H1 + f] + xv.y * W1[(q * 4 + 1) * H1 + f]
                      + xv.z * W1[(q * 4 + 2) * H1 + f] + xv.w * W1[(q * 4 + 3) * H1 + f];
            }
        }
        float s1 = 0.f, s2 = 0.f;
        #pragma unroll
        for (int f = 0; f < H1; f++) { s1 += h[f] * a1[f]; s2 += h[f] * a1[H1 + f]; }
        *(float4*)(h1 + (size_t)idx * H1) = make_float4(h[0], h[1], h[2], h[3]);
        f11[idx] = s1 * LOG2E_F;           // pre-scaled for exp2
        f21[idx] = s2 * LOG2E_F;
    }
}

// ---------------------------------------------------------------------------
// Attention v4: one k per block; stage h[k] + f2[k] in LDS once; one lane per
// 2 rows (R=2, 128 rows/block); 8 waves split j 8-ways (128 j each).
// Inner loop: wave-uniform ds_read broadcasts + per-row VALU; softmax without
// max-subtract (logits pre-scaled by log2e -> raw exp2; mask zeroes p after).
// The stage buffer and the partials buffer are both N*(F+1) floats -> union.
// ---------------------------------------------------------------------------
template <int F, bool FUSE>
__global__ __launch_bounds__(512, 4) void gat_attn4(
        const unsigned long long* __restrict__ maskT,  // [16][N]
        const float* __restrict__ h,    // [K,N,F]
        const float* __restrict__ f1,   // [K,N]  (x log2e)
        const float* __restrict__ f2,   // [K,N]  (x log2e)
        const float* __restrict__ W2,   // [4,8]  (FUSE only)
        const float* __restrict__ a2,   // [16]   (FUSE only)
        float* __restrict__ o_x,        // FUSE: h2 [K,N,8]; else out [K,N,F]
        float* __restrict__ o_f1,       // FUSE: f12 (x log2e)
        float* __restrict__ o_f2) {     // FUSE: f22 (x log2e)
    __shared__ float smem[N * (F + 1)];       // stage: h[N*F] + f2[N]; later: partials
    float* h_lds  = smem;
    float* f2_lds = smem + N * F;

    const int tid  = threadIdx.x;
    const int wave = tid >> 6;
    const int lane = tid & 63;
    const int k    = blockIdx.x >> 3;
    const int iset = blockIdx.x & 7;
    const int ibase = iset * 128;

    // ---- stage h[k], f2[k] into LDS (float4, coalesced) ----
    {
        const float4* hg = (const float4*)(h + (size_t)k * N * F);
        #pragma unroll
        for (int m = tid; m < N * F / 4; m += 512)
            ((float4*)h_lds)[m] = hg[m];
        if (tid < 256)
            ((float4*)f2_lds)[tid] = ((const float4*)(f2 + k * N))[tid];
    }
    __syncthreads();

    const int i0 = ibase + lane;
    const int i1 = i0 + 64;
    const float f1i0 = f1[k * N + i0];
    const float f1i1 = f1[k * N + i1];

    float s0 = 0.f, s1 = 0.f;
    float acc0[F], acc1[F];
    #pragma unroll
    for (int f = 0; f < F; f++) { acc0[f] = 0.f; acc1[f] = 0.f; }

    const int j0 = wave * 128;
    #pragma unroll
    for (int jw = 0; jw < 2; jw++) {
        const int jbase = j0 + jw * 64;
        const int mrow  = (jbase >> 6) * N;
        unsigned long long mw0 = maskT[mrow + i0];    // coalesced per wave
        unsigned long long mw1 = maskT[mrow + i1];
        #pragma unroll
        for (int half = 0; half < 2; half++) {
            const unsigned wb0 = half ? (unsigned)(mw0 >> 32) : (unsigned)mw0;
            const unsigned wb1 = half ? (unsigned)(mw1 >> 32) : (unsigned)mw1;
            const int jb = jbase + half * 32;
            #pragma unroll
            for (int t = 0; t < 32; t++) {
                float f2j = f2_lds[jb + t];                        // broadcast
                float4 h0 = ((const float4*)h_lds)[(jb + t) * (F / 4)];
                float4 h1v;
                if (F == 8) h1v = ((const float4*)h_lds)[(jb + t) * 2 + 1];
                // row 0
                {
                    float x = f1i0 + f2j;
                    float e = fmaxf(x, ALPHA_F * x);
                    float p = fast_exp2(e);
                    p = (wb0 & (1u << t)) ? p : 0.f;
                    s0 += p;
                    acc0[0] += p * h0.x; acc0[1] += p * h0.y;
                    acc0[2] += p * h0.z; acc0[3] += p * h0.w;
                    if (F == 8) {
                        acc0[4] += p * h1v.x; acc0[5] += p * h1v.y;
                        acc0[6] += p * h1v.z; acc0[7] += p * h1v.w;
                    }
                }
                // row 1
                {
                    float x = f1i1 + f2j;
                    float e = fmaxf(x, ALPHA_F * x);
                    float p = fast_exp2(e);
                    p = (wb1 & (1u << t)) ? p : 0.f;
                    s1 += p;
                    acc1[0] += p * h0.x; acc1[1] += p * h0.y;
                    acc1[2] += p * h0.z; acc1[3] += p * h0.w;
                    if (F == 8) {
                        acc1[4] += p * h1v.x; acc1[5] += p * h1v.y;
                        acc1[6] += p * h1v.z; acc1[7] += p * h1v.w;
                    }
                }
            }
        }
    }

    __syncthreads();   // all stage reads done before overwriting smem as partials

    // partials: [8 waves][128 rows][F+1]
    {
        float* p0 = smem + (wave * 128 + lane) * (F + 1);
        p0[0] = s0;
        #pragma unroll
        for (int f = 0; f < F; f++) p0[1 + f] = acc0[f];
        float* p1 = smem + (wave * 128 + lane + 64) * (F + 1);
        p1[0] = s1;
        #pragma unroll
        for (int f = 0; f < F; f++) p1[1 + f] = acc1[f];
    }
    __syncthreads();

    if (tid < 128) {
        const int r = tid;
        float st = 0.f;
        float at[F];
        #pragma unroll
        for (int f = 0; f < F; f++) at[f] = 0.f;
        #pragma unroll
        for (int w = 0; w < 8; w++) {
            const float* pp = smem + (w * 128 + r) * (F + 1);
            st += pp[0];
            #pragma unroll
            for (int f = 0; f < F; f++) at[f] += pp[1 + f];
        }
        const float inv = (st > 0.f) ? 1.f / st : 0.f;
        const int orow = k * N + ibase + r;
        float xo[F];
        #pragma unroll
        for (int f = 0; f < F; f++) xo[f] = fmaxf(at[f] * inv, 0.f);  // relu

        if constexpr (FUSE) {
            // layer-2 projection: h2 = xo(4) @ W2(4x8); logits vs a2 (x log2e)
            float hv[DOUT];
            #pragma unroll
            for (int f = 0; f < DOUT; f++) {
                hv[f] = xo[0] * W2[f]      + xo[1] * W2[8 + f]
                      + xo[2] * W2[16 + f] + xo[3] * W2[24 + f];
            }
            float t1 = 0.f, t2 = 0.f;
            #pragma unroll
            for (int f = 0; f < DOUT; f++) { t1 += hv[f] * a2[f]; t2 += hv[f] * a2[DOUT + f]; }
            float* op = o_x + (size_t)orow * DOUT;
            *(float4*)op       = make_float4(hv[0], hv[1], hv[2], hv[3]);
            *(float4*)(op + 4) = make_float4(hv[4], hv[5], hv[6], hv[7]);
            o_f1[orow] = t1 * LOG2E_F;
            o_f2[orow] = t2 * LOG2E_F;
        } else {
            float* op = o_x + (size_t)orow * F;
            *(float4*)op = make_float4(xo[0], xo[1], xo[2], xo[3]);
            if (F == 8)
                *(float4*)(op + 4) = make_float4(xo[4], xo[5], xo[6], xo[7]);
        }
    }
}

// ---------------------------------------------------------------------------
// FC1: y[k,c] = relu( x2[k,:] . wt[c,:] + b[c] ).  One wave per (k,c).
// ---------------------------------------------------------------------------
__global__ void fc1_kernel(const float* __restrict__ x2,
                           const float* __restrict__ wt,
                           const float* __restrict__ b,
                           float* __restrict__ y) {
    int bid  = blockIdx.x;            // k*54 + c
    int k    = bid / FC1;
    int c    = bid - k * FC1;
    int lane = threadIdx.x;
    const float4* x4 = (const float4*)(x2 + (size_t)k * N * DOUT);
    const float4* w4 = (const float4*)(wt + (size_t)c * N * DOUT);
    float s = 0.f;
    #pragma unroll 4
    for (int m = lane; m < (N * DOUT) / 4; m += 64) {
        float4 a = x4[m], w = w4[m];
        s += a.x * w.x + a.y * w.y + a.z * w.z + a.w * w.w;
    }
    #pragma unroll
    for (int off = 32; off > 0; off >>= 1) s += __shfl_xor(s, off);
    if (lane == 0) y[bid] = fmaxf(s + b[c], 0.f);
}

// ---------------------------------------------------------------------------
// Final: out[k,n] = y[k,:] . out_w[:,n] + out_b[n].  One thread per (k,n).
// ---------------------------------------------------------------------------
__global__ void fc2_kernel(const float* __restrict__ y,
                           const float* __restrict__ out_w,
                           const float* __restrict__ out_b,
                           float* __restrict__ out) {
    int n = blockIdx.x * blockDim.x + threadIdx.x;   // 0..1023
    int k = blockIdx.y;
    const float* yk = y + (size_t)k * FC1;
    float s = out_b[n];
    #pragma unroll 6
    for (int c = 0; c < FC1; c++) s += yk[c] * out_w[(size_t)c * N + n];
    out[(size_t)k * N + n] = s;
}

// ---------------------------------------------------------------------------
extern "C" void kernel_launch(void* const* d_in, const int* in_sizes, int n_in,
                              void* d_out, int out_size, void* d_ws, size_t ws_size,
                              hipStream_t stream) {
    const float* X     = (const float*)d_in[0];
    const int*   adj   = (const int*)  d_in[1];
    const float* W1    = (const float*)d_in[2];
    const float* a1    = (const float*)d_in[3];
    const float* W2    = (const float*)d_in[4];
    const float* a2    = (const float*)d_in[5];
    const float* fc1w  = (const float*)d_in[6];
    const float* fc1b  = (const float*)d_in[7];
    const float* outw  = (const float*)d_in[8];
    const float* outb  = (const float*)d_in[9];
    float* out = (float*)d_out;

    // Workspace layout (floats); ~8.05 MB total
    float* ws  = (float*)d_ws;
    float* h1  = ws;                       // 262144
    float* f11 = h1  + 262144;             // 65536
    float* f21 = f11 + 65536;              // 65536
    float* h2  = f21 + 65536;              // 524288
    float* f12 = h2  + 524288;             // 65536
    float* f22 = f12 + 65536;              // 65536
    float* x2  = f22 + 65536;              // 524288
    float* y   = x2  + 524288;             // 4096 (3456 used)
    float* wt  = y   + 4096;               // 442368
    unsigned long long* mT = (unsigned long long*)(wt + 442368);  // 16384 u64

    // 1) fused prep: mask pack (transposed) + fc1_w transpose + gat1 proj
    prep_kernel<<<dim3(3040), dim3(512), 0, stream>>>(
        adj, mT, fc1w, wt, X, W1, a1, h1, f11, f21);

    // 2) layer-1 attention (LDS-staged), fused with layer-2 projection
    gat_attn4<4, true><<<dim3(K * 8), dim3(512), 0, stream>>>(
        mT, h1, f11, f21, W2, a2, h2, f12, f22);

    // 3) layer-2 attention (LDS-staged)
    gat_attn4<8, false><<<dim3(K * 8), dim3(512), 0, stream>>>(
        mT, h2, f12, f22, nullptr, nullptr, x2, nullptr, nullptr);

    // 4) FC head
    fc1_kernel<<<dim3(K * FC1), dim3(64), 0, stream>>>(x2, wt, fc1b, y);
    fc2_kernel<<<dim3(N / 256, K), dim3(256), 0, stream>>>(y, outw, outb, out);
}

// Round 5
// 158.602 us; speedup vs baseline: 1.4817x; 1.1150x over previous
//
#include <hip/hip_runtime.h>

// Problem constants (from reference setup_inputs)
constexpr int K    = 64;
constexpr int N    = 1024;
constexpr int DIN  = 16;
constexpr int H1   = 4;
constexpr int DOUT = 8;
constexpr int FC1  = 54;

#define ALPHA_F   (0.01f)
#define LOG2E_F   (1.4426950408889634f)

__device__ inline float fast_exp2(float x) {
#if __has_builtin(__builtin_amdgcn_exp2f)
    return __builtin_amdgcn_exp2f(x);      // raw v_exp_f32
#else
    return __expf(x * 0.6931471805599453f);
#endif
}

// ---------------------------------------------------------------------------
// prep kernel: three independent jobs split by blockIdx range.
//  A) blocks [0,2048):    maskT[jw*N+i] = ballot bits of adj[i][jw*64+lane]
//  B) blocks [2048,2112): LDS-tile transpose fc1_w [8192,54] -> wt [54,8192]
//  C) blocks [2112,2240): gat1 projection: h1 = X@W1; f11/f21 logits *log2e
// ---------------------------------------------------------------------------
__global__ __launch_bounds__(512) void prep_kernel(
        const int* __restrict__ adj, unsigned long long* __restrict__ maskT,
        const float* __restrict__ fc1w, float* __restrict__ wt,
        const float* __restrict__ X, const float* __restrict__ W1,
        const float* __restrict__ a1,
        float* __restrict__ h1, float* __restrict__ f11, float* __restrict__ f21) {
    int b = blockIdx.x;
    if (b < 2048) {
        int wave = threadIdx.x >> 6, lane = threadIdx.x & 63;
        int wid = b * 8 + wave;            // 0..16383
        int jw  = wid >> 10;               // 0..15
        int i   = wid & 1023;
        int v = adj[i * N + (jw << 6) + lane];        // coalesced 256B/wave
        unsigned long long m = __ballot(v > 0);       // bit lane = adj>0
        if (lane == 0) maskT[jw * N + i] = m;
    } else if (b < 2112) {
        // transpose 128-row tile: coalesced read + coalesced write via LDS
        __shared__ float tile[128 * FC1];
        const int m0 = (b - 2048) * 128;
        const float* src = fc1w + (size_t)m0 * FC1;
        for (int idx = threadIdx.x; idx < 128 * FC1; idx += 512)
            tile[idx] = src[idx];                     // consecutive
        __syncthreads();
        for (int idx = threadIdx.x; idx < 128 * FC1; idx += 512) {
            int c = idx >> 7, mm = idx & 127;
            wt[(size_t)c * (N * DOUT) + m0 + mm] = tile[mm * FC1 + c];
        }
    } else {
        int idx = (b - 2112) * 512 + threadIdx.x;     // < 65536 : k*N+n
        const float4* x4 = (const float4*)(X + (size_t)idx * DIN);
        float h[H1] = {0.f, 0.f, 0.f, 0.f};
        #pragma unroll
        for (int q = 0; q < 4; q++) {
            float4 xv = x4[q];
            #pragma unroll
            for (int f = 0; f < H1; f++) {
                h[f] += xv.x * W1[(q * 4 + 0) * H1 + f] + xv.y * W1[(q * 4 + 1) * H1 + f]
                      + xv.z * W1[(q * 4 + 2) * H1 + f] + xv.w * W1[(q * 4 + 3) * H1 + f];
            }
        }
        float s1 = 0.f, s2 = 0.f;
        #pragma unroll
        for (int f = 0; f < H1; f++) { s1 += h[f] * a1[f]; s2 += h[f] * a1[H1 + f]; }
        *(float4*)(h1 + (size_t)idx * H1) = make_float4(h[0], h[1], h[2], h[3]);
        f11[idx] = s1 * LOG2E_F;           // pre-scaled for exp2
        f21[idx] = s2 * LOG2E_F;
    }
}

// ---------------------------------------------------------------------------
// Attention v5: one k per block, 4 ROWS PER LANE (256 rows/block, 256 blocks
// = 1/CU); stage h[k]+f2[k] in LDS once; 8 waves split j 8-ways (128 j each).
// Each ds_read broadcast now feeds 256 pairs (vs 128 in v4) -> LDS pipe cost
// halves. Softmax without max-subtract (logits pre-scaled by log2e -> raw
// exp2; mask zeroes p after exp). Partials combined in a second LDS buffer.
// ---------------------------------------------------------------------------
template <int F, bool FUSE>
__global__ __launch_bounds__(512, 2) void gat_attn5(
        const unsigned long long* __restrict__ maskT,  // [16][N]
        const float* __restrict__ h,    // [K,N,F]
        const float* __restrict__ f1,   // [K,N]  (x log2e)
        const float* __restrict__ f2,   // [K,N]  (x log2e)
        const float* __restrict__ W2,   // [4,8]  (FUSE only)
        const float* __restrict__ a2,   // [16]   (FUSE only)
        float* __restrict__ o_x,        // FUSE: h2 [K,N,8]; else out [K,N,F]
        float* __restrict__ o_f1,       // FUSE: f12 (x log2e)
        float* __restrict__ o_f2) {     // FUSE: f22 (x log2e)
    __shared__ float stage[N * (F + 1)];           // h[N*F] + f2[N]
    __shared__ float part[8 * 256 * (F + 1)];      // 8 waves x 256 rows
    float* h_lds  = stage;
    float* f2_lds = stage + N * F;

    const int tid  = threadIdx.x;
    const int wave = tid >> 6;
    const int lane = tid & 63;
    const int k    = blockIdx.x >> 2;
    const int iset = blockIdx.x & 3;
    const int ibase = iset * 256;

    // ---- stage h[k], f2[k] into LDS (float4, coalesced) ----
    {
        const float4* hg = (const float4*)(h + (size_t)k * N * F);
        #pragma unroll
        for (int m = tid; m < N * F / 4; m += 512)
            ((float4*)h_lds)[m] = hg[m];
        if (tid < 256)
            ((float4*)f2_lds)[tid] = ((const float4*)(f2 + k * N))[tid];
    }

    float f1r[4];
    #pragma unroll
    for (int r = 0; r < 4; r++) f1r[r] = f1[k * N + ibase + r * 64 + lane];

    float s[4] = {0.f, 0.f, 0.f, 0.f};
    float acc[4][F];
    #pragma unroll
    for (int r = 0; r < 4; r++)
        #pragma unroll
        for (int f = 0; f < F; f++) acc[r][f] = 0.f;

    __syncthreads();

    const int j0 = wave * 128;
    #pragma unroll
    for (int jw = 0; jw < 2; jw++) {
        const int jbase = j0 + jw * 64;
        const int mrow  = (jbase >> 6) * N + ibase + lane;
        unsigned long long mw[4];
        #pragma unroll
        for (int r = 0; r < 4; r++) mw[r] = maskT[mrow + r * 64];   // coalesced
        #pragma unroll
        for (int half = 0; half < 2; half++) {
            unsigned wb[4];
            #pragma unroll
            for (int r = 0; r < 4; r++)
                wb[r] = half ? (unsigned)(mw[r] >> 32) : (unsigned)mw[r];
            const int jb = jbase + half * 32;
            #pragma unroll 8
            for (int t = 0; t < 32; t++) {
                float f2j = f2_lds[jb + t];                        // broadcast
                float4 h0 = ((const float4*)h_lds)[(jb + t) * (F / 4)];
                float4 h1v;
                if (F == 8) h1v = ((const float4*)h_lds)[(jb + t) * 2 + 1];
                #pragma unroll
                for (int r = 0; r < 4; r++) {
                    float x = f1r[r] + f2j;
                    float e = fmaxf(x, ALPHA_F * x);
                    float p = fast_exp2(e);
                    p = (wb[r] & (1u << t)) ? p : 0.f;
                    s[r] += p;
                    acc[r][0] += p * h0.x; acc[r][1] += p * h0.y;
                    acc[r][2] += p * h0.z; acc[r][3] += p * h0.w;
                    if (F == 8) {
                        acc[r][4] += p * h1v.x; acc[r][5] += p * h1v.y;
                        acc[r][6] += p * h1v.z; acc[r][7] += p * h1v.w;
                    }
                }
            }
        }
    }

    // write partials: [wave][row][F+1]
    #pragma unroll
    for (int r = 0; r < 4; r++) {
        float* pp = part + (wave * 256 + r * 64 + lane) * (F + 1);
        pp[0] = s[r];
        #pragma unroll
        for (int f = 0; f < F; f++) pp[1 + f] = acc[r][f];
    }
    __syncthreads();

    if (tid < 256) {
        const int r = tid;
        float st = 0.f;
        float at[F];
        #pragma unroll
        for (int f = 0; f < F; f++) at[f] = 0.f;
        #pragma unroll
        for (int w = 0; w < 8; w++) {
            const float* pp = part + (w * 256 + r) * (F + 1);
            st += pp[0];
            #pragma unroll
            for (int f = 0; f < F; f++) at[f] += pp[1 + f];
        }
        const float inv = (st > 0.f) ? 1.f / st : 0.f;
        const int orow = k * N + ibase + r;
        float xo[F];
        #pragma unroll
        for (int f = 0; f < F; f++) xo[f] = fmaxf(at[f] * inv, 0.f);  // relu

        if constexpr (FUSE) {
            // layer-2 projection: h2 = xo(4) @ W2(4x8); logits vs a2 (x log2e)
            float hv[DOUT];
            #pragma unroll
            for (int f = 0; f < DOUT; f++) {
                hv[f] = xo[0] * W2[f]      + xo[1] * W2[8 + f]
                      + xo[2] * W2[16 + f] + xo[3] * W2[24 + f];
            }
            float t1 = 0.f, t2 = 0.f;
            #pragma unroll
            for (int f = 0; f < DOUT; f++) { t1 += hv[f] * a2[f]; t2 += hv[f] * a2[DOUT + f]; }
            float* op = o_x + (size_t)orow * DOUT;
            *(float4*)op       = make_float4(hv[0], hv[1], hv[2], hv[3]);
            *(float4*)(op + 4) = make_float4(hv[4], hv[5], hv[6], hv[7]);
            o_f1[orow] = t1 * LOG2E_F;
            o_f2[orow] = t2 * LOG2E_F;
        } else {
            float* op = o_x + (size_t)orow * F;
            *(float4*)op = make_float4(xo[0], xo[1], xo[2], xo[3]);
            if (F == 8)
                *(float4*)(op + 4) = make_float4(xo[4], xo[5], xo[6], xo[7]);
        }
    }
}

// ---------------------------------------------------------------------------
// FC1: y[k,c] = relu( x2[k,:] . wt[c,:] + b[c] ).
// One 256-thread block per (k,c): 4 waves split the 8192-dim, 2 accumulator
// chains per wave, butterfly + LDS combine.
// ---------------------------------------------------------------------------
__global__ __launch_bounds__(256) void fc1_kernel(
        const float* __restrict__ x2, const float* __restrict__ wt,
        const float* __restrict__ b, float* __restrict__ y) {
    const int bid  = blockIdx.x;            // k*54 + c
    const int k    = bid / FC1;
    const int c    = bid - k * FC1;
    const int wave = threadIdx.x >> 6;
    const int lane = threadIdx.x & 63;
    const float4* x4 = (const float4*)(x2 + (size_t)k * N * DOUT) + wave * 512 + lane;
    const float4* w4 = (const float4*)(wt + (size_t)c * N * DOUT) + wave * 512 + lane;
    float s0 = 0.f, s1 = 0.f;
    #pragma unroll
    for (int q = 0; q < 8; q += 2) {
        float4 a0 = x4[q * 64],      w0 = w4[q * 64];
        float4 a1 = x4[q * 64 + 64], w1 = w4[q * 64 + 64];
        s0 += a0.x * w0.x + a0.y * w0.y + a0.z * w0.z + a0.w * w0.w;
        s1 += a1.x * w1.x + a1.y * w1.y + a1.z * w1.z + a1.w * w1.w;
    }
    float s = s0 + s1;
    #pragma unroll
    for (int off = 32; off > 0; off >>= 1) s += __shfl_xor(s, off);
    __shared__ float red[4];
    if (lane == 0) red[wave] = s;
    __syncthreads();
    if (threadIdx.x == 0)
        y[bid] = fmaxf(red[0] + red[1] + red[2] + red[3] + b[c], 0.f);
}

// ---------------------------------------------------------------------------
// Final: out[k,n] = y[k,:] . out_w[:,n] + out_b[n].  One thread per (k,n).
// ---------------------------------------------------------------------------
__global__ void fc2_kernel(const float* __restrict__ y,
                           const float* __restrict__ out_w,
                           const float* __restrict__ out_b,
                           float* __restrict__ out) {
    int n = blockIdx.x * blockDim.x + threadIdx.x;   // 0..1023
    int k = blockIdx.y;
    const float* yk = y + (size_t)k * FC1;
    float s = out_b[n];
    #pragma unroll 6
    for (int c = 0; c < FC1; c++) s += yk[c] * out_w[(size_t)c * N + n];
    out[(size_t)k * N + n] = s;
}

// ---------------------------------------------------------------------------
extern "C" void kernel_launch(void* const* d_in, const int* in_sizes, int n_in,
                              void* d_out, int out_size, void* d_ws, size_t ws_size,
                              hipStream_t stream) {
    const float* X     = (const float*)d_in[0];
    const int*   adj   = (const int*)  d_in[1];
    const float* W1    = (const float*)d_in[2];
    const float* a1    = (const float*)d_in[3];
    const float* W2    = (const float*)d_in[4];
    const float* a2    = (const float*)d_in[5];
    const float* fc1w  = (const float*)d_in[6];
    const float* fc1b  = (const float*)d_in[7];
    const float* outw  = (const float*)d_in[8];
    const float* outb  = (const float*)d_in[9];
    float* out = (float*)d_out;

    // Workspace layout (floats); ~8.05 MB total
    float* ws  = (float*)d_ws;
    float* h1  = ws;                       // 262144
    float* f11 = h1  + 262144;             // 65536
    float* f21 = f11 + 65536;              // 65536
    float* h2  = f21 + 65536;              // 524288
    float* f12 = h2  + 524288;             // 65536
    float* f22 = f12 + 65536;              // 65536
    float* x2  = f22 + 65536;              // 524288
    float* y   = x2  + 524288;             // 4096 (3456 used)
    float* wt  = y   + 4096;               // 442368
    unsigned long long* mT = (unsigned long long*)(wt + 442368);  // 16384 u64

    // 1) fused prep: mask pack (transposed) + fc1_w transpose + gat1 proj
    prep_kernel<<<dim3(2240), dim3(512), 0, stream>>>(
        adj, mT, fc1w, wt, X, W1, a1, h1, f11, f21);

    // 2) layer-1 attention (LDS-staged, R=4), fused with layer-2 projection
    gat_attn5<4, true><<<dim3(K * 4), dim3(512), 0, stream>>>(
        mT, h1, f11, f21, W2, a2, h2, f12, f22);

    // 3) layer-2 attention (LDS-staged, R=4)
    gat_attn5<8, false><<<dim3(K * 4), dim3(512), 0, stream>>>(
        mT, h2, f12, f22, nullptr, nullptr, x2, nullptr, nullptr);

    // 4) FC head
    fc1_kernel<<<dim3(K * FC1), dim3(256), 0, stream>>>(x2, wt, fc1b, y);
    fc2_kernel<<<dim3(N / 256, K), dim3(256), 0, stream>>>(y, outw, outb, out);
}